// Round 15
// baseline (1578.364 us; speedup 1.0000x reference)
//
#include <hip/hip_runtime.h>
#include <hip/hip_bf16.h>

// Problem constants (B=8, N=4096, M=N/4, K=64, C_in=64, h=128)
#define BB   8
#define NN   4096
#define MM   1024
#define KK   64
#define CIN  64
#define HH   128

// f32 radius^2 predicate: largest f32 <= 0.2*0.2 (f64) = 0x3D23D70A.
#define R2F 0.039999999105930328f

// Inputs: f32, dict order. Output: f32, values bf16-rounded (matches np ref;
// R10-R14 passed with absmax 0.0).
static __device__ __forceinline__ float rnd_bf16(float v) {
    return __bfloat162float(__float2bfloat16(v));
}

// ---------------------------------------------------------------------------
// Kernel 1: FPS. R11 config (256 thr, 16 pts/thread, single rotating u64
// slot) with ONE change: in-wave butterfly pre-reduction before the atomic.
// R11-R14 ledger: 256-lane same-address atomicMax costs ~260cyc/step
// (conflicts 240/step); butterfly (6 shfl levels) + 4 per-wave atomics
// should cost ~150-200cyc and drop conflicts ~60x.
// Semantics unchanged: larger d wins, ties -> smaller index
// (= np.argmax first-occurrence); key = (bits(d)<<32) | ~idx.
// ---------------------------------------------------------------------------
__global__ __launch_bounds__(256) void fps_kernel(
    const float* __restrict__ pts,            // [B,3,N] f32
    float* __restrict__ centf,                // ws [B,M,3] f32 (exact)
    float* __restrict__ outc)                 // d_out (first B*M*3), f32
{
    const int b = blockIdx.x;
    const int t = threadIdx.x;
    __shared__ float lx[NN], ly[NN], lz[NN];
    __shared__ unsigned long long akey[4];

    const float* px = pts + (size_t)b * 3 * NN;
    float x[16], y[16], z[16], mind[16];
#pragma unroll
    for (int i = 0; i < 16; ++i) {
        int p = t + i * 256;                  // coalesced
        x[i] = px[p];
        y[i] = px[NN + p];
        z[i] = px[2 * NN + p];
        lx[p] = x[i]; ly[p] = y[i]; lz[p] = z[i];
        mind[i] = 3.4e38f;
    }
    if (t < 4) akey[t] = 0ULL;
    __syncthreads();

    float bx = lx[0], by = ly[0], bz = lz[0];

    for (int j = 0; j < MM; ++j) {
        if (t == 0) {
            int o = (b * MM + j) * 3;
            centf[o]    = bx; centf[o + 1] = by; centf[o + 2] = bz;
            outc[o]     = rnd_bf16(bx);
            outc[o + 1] = rnd_bf16(by);
            outc[o + 2] = rnd_bf16(bz);
            akey[(j + 2) & 3] = 0ULL;         // reset future slot (race-free)
        }
        float bd = -1.0f; int bi = 0;
#pragma unroll
        for (int i = 0; i < 16; ++i) {
            float dx = x[i] - bx, dy = y[i] - by, dz = z[i] - bz;
            // exact np order: (dx*dx + dy*dy) + dz*dz, RN, no fma
            float d = __fadd_rn(__fadd_rn(__fmul_rn(dx, dx), __fmul_rn(dy, dy)),
                                __fmul_rn(dz, dz));
            float md = fminf(mind[i], d);
            mind[i] = md;
            if (md > bd) { bd = md; bi = t + i * 256; }  // strict >: smaller idx
        }
        // in-wave butterfly argmax (ties -> smaller index)
#pragma unroll
        for (int off = 32; off >= 1; off >>= 1) {
            float ov = __shfl_xor(bd, off);
            int   oi = __shfl_xor(bi, off);
            if (ov > bd || (ov == bd && oi < bi)) { bd = ov; bi = oi; }
        }
        if ((t & 63) == 0) {                  // one atomic per wave (4 total)
            unsigned long long key =
                ((unsigned long long)__float_as_uint(bd) << 32) |
                (unsigned long long)(0xFFFFFFFFu - (unsigned)bi);
            atomicMax(&akey[j & 3], key);
        }
        __syncthreads();
        unsigned long long bk = akey[j & 3];
        int best = (int)(0xFFFFFFFFu - (unsigned)(bk & 0xFFFFFFFFULL));
        bx = lx[best]; by = ly[best]; bz = lz[best];
    }
}

// ---------------------------------------------------------------------------
// Kernel 2: per-point feature MLP cache (compute once per point; 16x fewer
// FLOPs than per-group). bf16 output is EXACT under the group max (RNE
// monotone => round-then-max == max-then-round). ~20us, not a bottleneck.
// ---------------------------------------------------------------------------
__global__ __launch_bounds__(256) void featmlp_kernel(
    const float* __restrict__ feat,            // [B,CIN,N] f32
    const float* __restrict__ fw1, const float* __restrict__ fb1,
    const float* __restrict__ fw2, const float* __restrict__ fb2,
    const float* __restrict__ fw3, const float* __restrict__ fb3,
    __hip_bfloat16* __restrict__ out)          // ws [B,N,HH] bf16
{
    __shared__ float w1[CIN * CIN], w2[CIN * CIN];
    const int tid = threadIdx.x;
    for (int i = tid; i < CIN * CIN; i += 256) { w1[i] = fw1[i]; w2[i] = fw2[i]; }
    __syncthreads();

    const int gid = blockIdx.x * 256 + tid;    // b*N + n
    const int b = gid >> 12, n = gid & (NN - 1);
    const float* fp = feat + (size_t)b * CIN * NN + n;

    float f[CIN];
#pragma unroll
    for (int c = 0; c < CIN; ++c) f[c] = fp[(size_t)c * NN];

    float h1[CIN];
    for (int o = 0; o < CIN; ++o) {
        float acc = fb1[o];
#pragma unroll
        for (int c = 0; c < CIN; ++c) acc = fmaf(f[c], w1[o * CIN + c], acc);
        h1[o] = fmaxf(acc, 0.f);
    }
    float h2[CIN];
    for (int o = 0; o < CIN; ++o) {
        float acc = fb2[o];
#pragma unroll
        for (int c = 0; c < CIN; ++c) acc = fmaf(h1[c], w2[o * CIN + c], acc);
        h2[o] = fmaxf(acc, 0.f);
    }
    __hip_bfloat16* op = out + (size_t)gid * HH;
    for (int o = 0; o < HH; ++o) {
        float acc = fb3[o];
#pragma unroll
        for (int c = 0; c < CIN; ++c) acc = fmaf(h2[c], fw3[o * CIN + c], acc);
        op[o] = __float2bfloat16(acc);
    }
}

// ---------------------------------------------------------------------------
// Kernel 3: fused ball-query + point MLP + max + feature gather-max.
// Byte-identical to R14 (ball-query variants measured neutral twice; the
// ~500us here is latency in L2/L3/gather -- separate investigation).
// ---------------------------------------------------------------------------
#define H2S 68
__global__ __launch_bounds__(64) void groupnet_kernel(
    const float* __restrict__ pts,             // [B,3,N] f32
    const float* __restrict__ centf,           // ws [B,M,3] f32
    const __hip_bfloat16* __restrict__ fout,   // ws [B,N,HH] bf16
    const float* __restrict__ pw1, const float* __restrict__ pb1,
    const float* __restrict__ pw2, const float* __restrict__ pb2,
    const float* __restrict__ pw3, const float* __restrict__ pb3,
    float* __restrict__ outf)                  // d_out + B*M*3: [B,256,M] f32
{
    __shared__ float h2s[KK * H2S];
    __shared__ int   sels[KK];

    const int g = blockIdx.x;                  // b*M + m
    const int b = g >> 10, m = g & (MM - 1);
    const int lane = threadIdx.x;

    const float* pts_b = pts + (size_t)b * 3 * NN;
    const float cx = centf[(size_t)g * 3];
    const float cy = centf[(size_t)g * 3 + 1];
    const float cz = centf[(size_t)g * 3 + 2];

    // ---- 1) ball query: fixed 64 chunks, 2-stage software pipeline ----
    int cnt = 0, first = 0;
    bool have_first = false;
    float vx = pts_b[lane], vy = pts_b[NN + lane], vz = pts_b[2 * NN + lane];
    for (int base = 0; base < NN; base += 64) {
        float nx = 0.f, ny = 0.f, nz = 0.f;
        if (base + 64 < NN) {                  // prefetch next chunk
            int p = base + 64 + lane;
            nx = pts_b[p]; ny = pts_b[NN + p]; nz = pts_b[2 * NN + p];
        }
        float dx = vx - cx, dy = vy - cy, dz = vz - cz;
        float d2 = __fadd_rn(__fadd_rn(__fmul_rn(dx, dx), __fmul_rn(dy, dy)),
                             __fmul_rn(dz, dz));
        bool in = (d2 <= R2F);
        unsigned long long mask = __ballot(in);
        if (!have_first && mask != 0ULL) {
            first = base + (int)__builtin_ctzll(mask);
            have_first = true;
        }
        int pos = cnt + (int)__popcll(mask & ((1ULL << lane) - 1ULL));
        if (in && pos < KK) sels[pos] = base + lane;
        cnt += (int)__popcll(mask);
        vx = nx; vy = ny; vz = nz;
    }
    if (cnt < KK) {
        // centroid is itself a point (d2 == 0) -> have_first always true
        for (int q = cnt + lane; q < KK; q += 64) sels[q] = first;
    }
    __syncthreads();                           // sels visible

    const int s = sels[lane];
    float* ob = outf + (size_t)b * 256 * MM + m;

    // ---- 2) point path layers 1-2 (lane = group slot k); pw2 via K$ ----
    {
        const float x = pts_b[s]          - cx;
        const float y = pts_b[NN + s]     - cy;
        const float z = pts_b[2 * NN + s] - cz;
        float h1[CIN];
#pragma unroll
        for (int o = 0; o < CIN; ++o) {
            float acc = pb1[o];
            acc = fmaf(x, pw1[o * 3 + 0], acc);
            acc = fmaf(y, pw1[o * 3 + 1], acc);
            acc = fmaf(z, pw1[o * 3 + 2], acc);
            h1[o] = fmaxf(acc, 0.f);
        }
        for (int o4 = 0; o4 < CIN / 4; ++o4) {
            float4 hv; float* hp = &hv.x;
#pragma unroll
            for (int q = 0; q < 4; ++q) {
                int o = o4 * 4 + q;
                float acc = pb2[o];
#pragma unroll
                for (int c = 0; c < CIN; ++c) acc = fmaf(h1[c], pw2[o * CIN + c], acc);
                hp[q] = fmaxf(acc, 0.f);
            }
            *(float4*)&h2s[lane * H2S + o4 * 4] = hv;
        }
    }
    __syncthreads();

    // ---- 3) point layer 3 + group max -> out ch 128..255 (k-split ILP) ----
    {
        float w3a[CIN], w3b[CIN];
#pragma unroll
        for (int c = 0; c < CIN; ++c) {
            w3a[c] = pw3[(size_t)lane * CIN + c];
            w3b[c] = pw3[(size_t)(lane + 64) * CIN + c];
        }
        const float b3a = pb3[lane], b3b = pb3[lane + 64];
        float pa0 = -3.4e38f, pb0 = -3.4e38f;  // k in [0,32)
        float pa1 = -3.4e38f, pb1v = -3.4e38f; // k in [32,64)
        for (int k = 0; k < KK / 2; ++k) {
            float va0 = b3a, vb0 = b3b, va1 = b3a, vb1 = b3b;
#pragma unroll
            for (int c4 = 0; c4 < CIN / 4; ++c4) {
                float4 h0 = *(const float4*)&h2s[k * H2S + c4 * 4];
                float4 h1 = *(const float4*)&h2s[(k + 32) * H2S + c4 * 4];
                va0 = fmaf(h0.x, w3a[c4*4+0], va0); vb0 = fmaf(h0.x, w3b[c4*4+0], vb0);
                va1 = fmaf(h1.x, w3a[c4*4+0], va1); vb1 = fmaf(h1.x, w3b[c4*4+0], vb1);
                va0 = fmaf(h0.y, w3a[c4*4+1], va0); vb0 = fmaf(h0.y, w3b[c4*4+1], vb0);
                va1 = fmaf(h1.y, w3a[c4*4+1], va1); vb1 = fmaf(h1.y, w3b[c4*4+1], vb1);
                va0 = fmaf(h0.z, w3a[c4*4+2], va0); vb0 = fmaf(h0.z, w3b[c4*4+2], vb0);
                va1 = fmaf(h1.z, w3a[c4*4+2], va1); vb1 = fmaf(h1.z, w3b[c4*4+2], vb1);
                va0 = fmaf(h0.w, w3a[c4*4+3], va0); vb0 = fmaf(h0.w, w3b[c4*4+3], vb0);
                va1 = fmaf(h1.w, w3a[c4*4+3], va1); vb1 = fmaf(h1.w, w3b[c4*4+3], vb1);
            }
            pa0 = fmaxf(pa0, va0); pb0  = fmaxf(pb0,  vb0);
            pa1 = fmaxf(pa1, va1); pb1v = fmaxf(pb1v, vb1);
        }
        ob[(size_t)(128 + lane) * MM] = rnd_bf16(fmaxf(pa0, pa1));
        ob[(size_t)(192 + lane) * MM] = rnd_bf16(fmaxf(pb0, pb1v));
    }

    // ---- 4) feature gather-max (bf16 cache), k-split -> out ch 0..127 ----
    {
        const __hip_bfloat16* fb_ = fout + (size_t)b * NN * HH;
        float fa0 = -3.4e38f, fb0 = -3.4e38f;
        float fa1 = -3.4e38f, fb1v = -3.4e38f;
        for (int k = 0; k < KK / 2; ++k) {
            const __hip_bfloat16* fp0 = fb_ + (size_t)sels[k] * HH;
            const __hip_bfloat16* fp1 = fb_ + (size_t)sels[k + 32] * HH;
            fa0  = fmaxf(fa0,  __bfloat162float(fp0[lane]));
            fb0  = fmaxf(fb0,  __bfloat162float(fp0[lane + 64]));
            fa1  = fmaxf(fa1,  __bfloat162float(fp1[lane]));
            fb1v = fmaxf(fb1v, __bfloat162float(fp1[lane + 64]));
        }
        ob[(size_t)lane * MM]        = fmaxf(fa0, fa1);  // values already bf16-exact
        ob[(size_t)(lane + 64) * MM] = fmaxf(fb0, fb1v);
    }
}

extern "C" void kernel_launch(void* const* d_in, const int* in_sizes, int n_in,
                              void* d_out, int out_size, void* d_ws, size_t ws_size,
                              hipStream_t stream) {
    const float* pts  = (const float*)d_in[0];
    const float* feat = (const float*)d_in[1];
    const float* pw1  = (const float*)d_in[2];
    const float* pb1  = (const float*)d_in[3];
    const float* pw2  = (const float*)d_in[4];
    const float* pb2  = (const float*)d_in[5];
    const float* pw3  = (const float*)d_in[6];
    const float* pb3  = (const float*)d_in[7];
    const float* fw1  = (const float*)d_in[8];
    const float* fb1  = (const float*)d_in[9];
    const float* fw2  = (const float*)d_in[10];
    const float* fb2  = (const float*)d_in[11];
    const float* fw3  = (const float*)d_in[12];
    const float* fb3  = (const float*)d_in[13];

    float* out = (float*)d_out;                // f32 output

    // ws: [0,96KB) f32 centroids; [96KB, +8.39MB) bf16 feature-MLP cache.
    float* centf = (float*)d_ws;
    __hip_bfloat16* fout = (__hip_bfloat16*)((char*)d_ws + (size_t)BB * MM * 3 * 4);

    featmlp_kernel<<<(BB * NN) / 256, 256, 0, stream>>>(
        feat, fw1, fb1, fw2, fb2, fw3, fb3, fout);
    fps_kernel<<<BB, 256, 0, stream>>>(pts, centf, out);
    groupnet_kernel<<<BB * MM, 64, 0, stream>>>(
        pts, centf, fout,
        pw1, pb1, pw2, pb2, pw3, pb3,
        out + (size_t)BB * MM * 3);
}

// Round 16
// 1102.420 us; speedup vs baseline: 1.4317x; 1.4317x over previous
//
#include <hip/hip_runtime.h>
#include <hip/hip_bf16.h>

// Problem constants (B=8, N=4096, M=N/4, K=64, C_in=64, h=128)
#define BB   8
#define NN   4096
#define MM   1024
#define KK   64
#define CIN  64
#define HH   128

// f32 radius^2 predicate: largest f32 <= 0.2*0.2 (f64) = 0x3D23D70A.
#define R2F 0.039999999105930328f

// Inputs: f32, dict order. Output: f32, values bf16-rounded (matches np ref).
static __device__ __forceinline__ float rnd_bf16(float v) {
    return __bfloat162float(__float2bfloat16(v));
}
// Manual RNE f32->bf16 (finite inputs only; matches RNE for our h2 values).
static __device__ __forceinline__ unsigned int bf16bits(float v) {
    unsigned int u = __float_as_uint(v);
    return (u + 0x7FFFu + ((u >> 16) & 1u)) >> 16;
}

// ---------------------------------------------------------------------------
// Kernel 1: FPS -- exact R11 config (best measured 631us). Ledger: R12
// 512thr=790, R13 4-slot+f4=694, R15 shfl-butterfly=1068 (gfx950 ds_permute
// shuffles ~100cyc each; 256-lane same-addr LDS atomicMax only ~260cyc).
// DO NOT replace the atomic with shuffles.
// Key = (bits(d)<<32) | ~idx: u64 max == largest d, ties -> smallest idx
// (= np.argmax first-occurrence; d >= 0 so IEEE bits monotone).
// ---------------------------------------------------------------------------
__global__ __launch_bounds__(256) void fps_kernel(
    const float* __restrict__ pts,            // [B,3,N] f32
    float* __restrict__ centf,                // ws [B,M,3] f32 (exact)
    float* __restrict__ outc)                 // d_out (first B*M*3), f32
{
    const int b = blockIdx.x;
    const int t = threadIdx.x;
    __shared__ float lx[NN], ly[NN], lz[NN];
    __shared__ unsigned long long akey[4];

    const float* px = pts + (size_t)b * 3 * NN;
    float x[16], y[16], z[16], mind[16];
#pragma unroll
    for (int i = 0; i < 16; ++i) {
        int p = t + i * 256;                  // coalesced
        x[i] = px[p];
        y[i] = px[NN + p];
        z[i] = px[2 * NN + p];
        lx[p] = x[i]; ly[p] = y[i]; lz[p] = z[i];
        mind[i] = 3.4e38f;
    }
    if (t < 4) akey[t] = 0ULL;
    __syncthreads();

    float bx = lx[0], by = ly[0], bz = lz[0];

    for (int j = 0; j < MM; ++j) {
        if (t == 0) {
            int o = (b * MM + j) * 3;
            centf[o]    = bx; centf[o + 1] = by; centf[o + 2] = bz;
            outc[o]     = rnd_bf16(bx);
            outc[o + 1] = rnd_bf16(by);
            outc[o + 2] = rnd_bf16(bz);
            akey[(j + 2) & 3] = 0ULL;         // reset future slot (race-free)
        }
        float bd = -1.0f; int bi = 0;
#pragma unroll
        for (int i = 0; i < 16; ++i) {
            float dx = x[i] - bx, dy = y[i] - by, dz = z[i] - bz;
            // exact np order: (dx*dx + dy*dy) + dz*dz, RN, no fma
            float d = __fadd_rn(__fadd_rn(__fmul_rn(dx, dx), __fmul_rn(dy, dy)),
                                __fmul_rn(dz, dz));
            float md = fminf(mind[i], d);
            mind[i] = md;
            if (md > bd) { bd = md; bi = t + i * 256; }  // strict >: smaller idx
        }
        unsigned long long key =
            ((unsigned long long)__float_as_uint(bd) << 32) |
            (unsigned long long)(0xFFFFFFFFu - (unsigned)bi);
        atomicMax(&akey[j & 3], key);
        __syncthreads();
        unsigned long long bk = akey[j & 3];
        int best = (int)(0xFFFFFFFFu - (unsigned)(bk & 0xFFFFFFFFULL));
        bx = lx[best]; by = ly[best]; bz = lz[best];
    }
}

// ---------------------------------------------------------------------------
// Kernel 2: per-point feature MLP cache. bf16 output EXACT under group max
// (RNE monotone). ~20us, not a bottleneck.
// ---------------------------------------------------------------------------
__global__ __launch_bounds__(256) void featmlp_kernel(
    const float* __restrict__ feat,            // [B,CIN,N] f32
    const float* __restrict__ fw1, const float* __restrict__ fb1,
    const float* __restrict__ fw2, const float* __restrict__ fb2,
    const float* __restrict__ fw3, const float* __restrict__ fb3,
    __hip_bfloat16* __restrict__ out)          // ws [B,N,HH] bf16
{
    __shared__ float w1[CIN * CIN], w2[CIN * CIN];
    const int tid = threadIdx.x;
    for (int i = tid; i < CIN * CIN; i += 256) { w1[i] = fw1[i]; w2[i] = fw2[i]; }
    __syncthreads();

    const int gid = blockIdx.x * 256 + tid;    // b*N + n
    const int b = gid >> 12, n = gid & (NN - 1);
    const float* fp = feat + (size_t)b * CIN * NN + n;

    float f[CIN];
#pragma unroll
    for (int c = 0; c < CIN; ++c) f[c] = fp[(size_t)c * NN];

    float h1[CIN];
    for (int o = 0; o < CIN; ++o) {
        float acc = fb1[o];
#pragma unroll
        for (int c = 0; c < CIN; ++c) acc = fmaf(f[c], w1[o * CIN + c], acc);
        h1[o] = fmaxf(acc, 0.f);
    }
    float h2[CIN];
    for (int o = 0; o < CIN; ++o) {
        float acc = fb2[o];
#pragma unroll
        for (int c = 0; c < CIN; ++c) acc = fmaf(h1[c], w2[o * CIN + c], acc);
        h2[o] = fmaxf(acc, 0.f);
    }
    __hip_bfloat16* op = out + (size_t)gid * HH;
    for (int o = 0; o < HH; ++o) {
        float acc = fb3[o];
#pragma unroll
        for (int c = 0; c < CIN; ++c) acc = fmaf(h2[c], fw3[o * CIN + c], acc);
        op[o] = __float2bfloat16(acc);
    }
}

// ---------------------------------------------------------------------------
// Kernel 3: fused ball-query + point MLP + max + feature gather-max.
// vs R14: h2s stored as PACKED BF16 (u32 pairs, row stride 36 u32 = 144B,
// 16B-aligned) -> LDS 17.7KB -> 9.5KB -> occupancy ~9 -> ~16 blocks/CU.
// groupnet was latency-bound at 22% issue efficiency; occupancy is the lever.
// h2 bf16-rounding adds ~0.013 abs error to point-path outputs (threshold
// >= 0.05) -- discrete selections and feature path untouched.
// Phase 2 now runs 8 parallel accumulator chains (was 4).
// ---------------------------------------------------------------------------
#define H2SU 36   // u32 stride per k-row (32 data + 4 pad, 16B aligned)
__global__ __launch_bounds__(64) void groupnet_kernel(
    const float* __restrict__ pts,             // [B,3,N] f32
    const float* __restrict__ centf,           // ws [B,M,3] f32
    const __hip_bfloat16* __restrict__ fout,   // ws [B,N,HH] bf16
    const float* __restrict__ pw1, const float* __restrict__ pb1,
    const float* __restrict__ pw2, const float* __restrict__ pb2,
    const float* __restrict__ pw3, const float* __restrict__ pb3,
    float* __restrict__ outf)                  // d_out + B*M*3: [B,256,M] f32
{
    __shared__ unsigned int h2s[KK * H2SU];    // packed bf16 pairs, 9.2KB
    __shared__ int sels[KK];

    const int g = blockIdx.x;                  // b*M + m
    const int b = g >> 10, m = g & (MM - 1);
    const int lane = threadIdx.x;

    const float* pts_b = pts + (size_t)b * 3 * NN;
    const float cx = centf[(size_t)g * 3];
    const float cy = centf[(size_t)g * 3 + 1];
    const float cz = centf[(size_t)g * 3 + 2];

    // ---- 1) ball query: fixed 64 chunks, 2-stage software pipeline ----
    int cnt = 0, first = 0;
    bool have_first = false;
    float vx = pts_b[lane], vy = pts_b[NN + lane], vz = pts_b[2 * NN + lane];
    for (int base = 0; base < NN; base += 64) {
        float nx = 0.f, ny = 0.f, nz = 0.f;
        if (base + 64 < NN) {                  // prefetch next chunk
            int p = base + 64 + lane;
            nx = pts_b[p]; ny = pts_b[NN + p]; nz = pts_b[2 * NN + p];
        }
        float dx = vx - cx, dy = vy - cy, dz = vz - cz;
        float d2 = __fadd_rn(__fadd_rn(__fmul_rn(dx, dx), __fmul_rn(dy, dy)),
                             __fmul_rn(dz, dz));
        bool in = (d2 <= R2F);
        unsigned long long mask = __ballot(in);
        if (!have_first && mask != 0ULL) {
            first = base + (int)__builtin_ctzll(mask);
            have_first = true;
        }
        int pos = cnt + (int)__popcll(mask & ((1ULL << lane) - 1ULL));
        if (in && pos < KK) sels[pos] = base + lane;
        cnt += (int)__popcll(mask);
        vx = nx; vy = ny; vz = nz;
    }
    if (cnt < KK) {
        for (int q = cnt + lane; q < KK; q += 64) sels[q] = first;
    }
    __syncthreads();                           // sels visible

    const int s = sels[lane];
    float* ob = outf + (size_t)b * 256 * MM + m;

    // ---- 2) point path layers 1-2 (lane = slot k); 8 parallel chains ----
    {
        const float x = pts_b[s]          - cx;
        const float y = pts_b[NN + s]     - cy;
        const float z = pts_b[2 * NN + s] - cz;
        float h1[CIN];
#pragma unroll
        for (int o = 0; o < CIN; ++o) {
            float acc = pb1[o];
            acc = fmaf(x, pw1[o * 3 + 0], acc);
            acc = fmaf(y, pw1[o * 3 + 1], acc);
            acc = fmaf(z, pw1[o * 3 + 2], acc);
            h1[o] = fmaxf(acc, 0.f);
        }
        for (int o8 = 0; o8 < CIN / 8; ++o8) { // 8 outputs per iter
            float a[8];
#pragma unroll
            for (int q = 0; q < 8; ++q) a[q] = pb2[o8 * 8 + q];
            for (int c = 0; c < CIN; ++c) {
                float hc = h1[c];
#pragma unroll
                for (int q = 0; q < 8; ++q)
                    a[q] = fmaf(hc, pw2[(o8 * 8 + q) * CIN + c], a[q]);
            }
            uint4 pk;
            pk.x = bf16bits(fmaxf(a[0], 0.f)) | (bf16bits(fmaxf(a[1], 0.f)) << 16);
            pk.y = bf16bits(fmaxf(a[2], 0.f)) | (bf16bits(fmaxf(a[3], 0.f)) << 16);
            pk.z = bf16bits(fmaxf(a[4], 0.f)) | (bf16bits(fmaxf(a[5], 0.f)) << 16);
            pk.w = bf16bits(fmaxf(a[6], 0.f)) | (bf16bits(fmaxf(a[7], 0.f)) << 16);
            *(uint4*)&h2s[lane * H2SU + o8 * 4] = pk;
        }
    }
    __syncthreads();

    // ---- 3) point layer 3 + group max -> out ch 128..255 (k-split ILP) ----
    {
        float w3a[CIN], w3b[CIN];
#pragma unroll
        for (int c = 0; c < CIN; ++c) {
            w3a[c] = pw3[(size_t)lane * CIN + c];
            w3b[c] = pw3[(size_t)(lane + 64) * CIN + c];
        }
        const float b3a = pb3[lane], b3b = pb3[lane + 64];
        float pa0 = -3.4e38f, pb0 = -3.4e38f;  // k in [0,32)
        float pa1 = -3.4e38f, pb1v = -3.4e38f; // k in [32,64)
        for (int k = 0; k < KK / 2; ++k) {
            float va0 = b3a, vb0 = b3b, va1 = b3a, vb1 = b3b;
#pragma unroll
            for (int u4 = 0; u4 < 8; ++u4) {   // 8 uint4 = 32 u32 = 64 bf16
                uint4 p0 = *(const uint4*)&h2s[k * H2SU + u4 * 4];
                uint4 p1 = *(const uint4*)&h2s[(k + 32) * H2SU + u4 * 4];
                const unsigned int* w0 = &p0.x;
                const unsigned int* w1 = &p1.x;
#pragma unroll
                for (int j = 0; j < 4; ++j) {
                    int c = u4 * 8 + j * 2;
                    float h0lo = __uint_as_float(w0[j] << 16);
                    float h0hi = __uint_as_float(w0[j] & 0xFFFF0000u);
                    float h1lo = __uint_as_float(w1[j] << 16);
                    float h1hi = __uint_as_float(w1[j] & 0xFFFF0000u);
                    va0 = fmaf(h0lo, w3a[c],     va0); vb0 = fmaf(h0lo, w3b[c],     vb0);
                    va1 = fmaf(h1lo, w3a[c],     va1); vb1 = fmaf(h1lo, w3b[c],     vb1);
                    va0 = fmaf(h0hi, w3a[c + 1], va0); vb0 = fmaf(h0hi, w3b[c + 1], vb0);
                    va1 = fmaf(h1hi, w3a[c + 1], va1); vb1 = fmaf(h1hi, w3b[c + 1], vb1);
                }
            }
            pa0 = fmaxf(pa0, va0); pb0  = fmaxf(pb0,  vb0);
            pa1 = fmaxf(pa1, va1); pb1v = fmaxf(pb1v, vb1);
        }
        ob[(size_t)(128 + lane) * MM] = rnd_bf16(fmaxf(pa0, pa1));
        ob[(size_t)(192 + lane) * MM] = rnd_bf16(fmaxf(pb0, pb1v));
    }

    // ---- 4) feature gather-max (bf16 cache), k-split -> out ch 0..127 ----
    {
        const __hip_bfloat16* fb_ = fout + (size_t)b * NN * HH;
        float fa0 = -3.4e38f, fb0 = -3.4e38f;
        float fa1 = -3.4e38f, fb1v = -3.4e38f;
        for (int k = 0; k < KK / 2; ++k) {
            const __hip_bfloat16* fp0 = fb_ + (size_t)sels[k] * HH;
            const __hip_bfloat16* fp1 = fb_ + (size_t)sels[k + 32] * HH;
            fa0  = fmaxf(fa0,  __bfloat162float(fp0[lane]));
            fb0  = fmaxf(fb0,  __bfloat162float(fp0[lane + 64]));
            fa1  = fmaxf(fa1,  __bfloat162float(fp1[lane]));
            fb1v = fmaxf(fb1v, __bfloat162float(fp1[lane + 64]));
        }
        ob[(size_t)lane * MM]        = fmaxf(fa0, fa1);  // values already bf16-exact
        ob[(size_t)(lane + 64) * MM] = fmaxf(fb0, fb1v);
    }
}

extern "C" void kernel_launch(void* const* d_in, const int* in_sizes, int n_in,
                              void* d_out, int out_size, void* d_ws, size_t ws_size,
                              hipStream_t stream) {
    const float* pts  = (const float*)d_in[0];
    const float* feat = (const float*)d_in[1];
    const float* pw1  = (const float*)d_in[2];
    const float* pb1  = (const float*)d_in[3];
    const float* pw2  = (const float*)d_in[4];
    const float* pb2  = (const float*)d_in[5];
    const float* pw3  = (const float*)d_in[6];
    const float* pb3  = (const float*)d_in[7];
    const float* fw1  = (const float*)d_in[8];
    const float* fb1  = (const float*)d_in[9];
    const float* fw2  = (const float*)d_in[10];
    const float* fb2  = (const float*)d_in[11];
    const float* fw3  = (const float*)d_in[12];
    const float* fb3  = (const float*)d_in[13];

    float* out = (float*)d_out;                // f32 output

    // ws: [0,96KB) f32 centroids; [96KB, +8.39MB) bf16 feature-MLP cache.
    float* centf = (float*)d_ws;
    __hip_bfloat16* fout = (__hip_bfloat16*)((char*)d_ws + (size_t)BB * MM * 3 * 4);

    featmlp_kernel<<<(BB * NN) / 256, 256, 0, stream>>>(
        feat, fw1, fb1, fw2, fb2, fw3, fb3, fout);
    fps_kernel<<<BB, 256, 0, stream>>>(pts, centf, out);
    groupnet_kernel<<<BB * MM, 64, 0, stream>>>(
        pts, centf, fout,
        pw1, pb1, pw2, pb2, pw3, pb3,
        out + (size_t)BB * MM * 3);
}